// Round 10
// baseline (802.188 us; speedup 1.0000x reference)
//
#include <hip/hip_runtime.h>
#include <hip/hip_bf16.h>

// GCN: conv1(512->16) + relu + conv2(16->5) + mlp(5->32->5) + log_softmax
// out[dst] = dinv[dst]*(sum_{src in N(dst)} hs[src] + hs[dst]) + b,  hs = dinv*(h@W)
// CSR-free aggregation: segmented bucket sort (512 dst-range buckets) then
// per-bucket LDS scatter-accumulate (no node-level sort, no ssrc/rowptr).
// gemm1 via MFMA with pre-packed register-resident W1.

#define F_IN 512
#define HDIM 16
#define CDIM 5
#define NB   512       // dst-range buckets
#define NPB_MAX 200    // max nodes per bucket supported by LDS arrays
#define SEG  16384     // per-bucket segment capacity (mean 12500, +34 sigma)
#define GWP_STRIDE 16  // pad gwp counters to one per 64B line
#define EPT  10        // edges per thread in binscatter
#define SCHUNK (1024*EPT)

typedef __attribute__((ext_vector_type(8))) short short8;
typedef __attribute__((ext_vector_type(4))) float floatx4;

__device__ inline float bf2f(unsigned short u){
  unsigned int i = ((unsigned int)u) << 16; float f; __builtin_memcpy(&f, &i, 4); return f;
}
__device__ inline unsigned short f2bf(float x){
  unsigned int i; __builtin_memcpy(&i, &x, 4);
  unsigned int r = i + 0x7FFFu + ((i >> 16) & 1u);
  return (unsigned short)(r >> 16);
}
__device__ inline float ulo(unsigned int u){
  unsigned int v = u << 16; float f; __builtin_memcpy(&f, &v, 4); return f;
}
__device__ inline float uhi(unsigned int u){
  unsigned int v = u & 0xFFFF0000u; float f; __builtin_memcpy(&f, &v, 4); return f;
}
__device__ inline short8 pack8(float4 u0, float4 u1){
  unsigned short o[8] = {f2bf(u0.x), f2bf(u0.y), f2bf(u0.z), f2bf(u0.w),
                         f2bf(u1.x), f2bf(u1.y), f2bf(u1.z), f2bf(u1.w)};
  short8 r; __builtin_memcpy(&r, o, 16); return r;
}

// ---- single block: init flag + gwp segment bases + detect int64/int32 layout
__global__ __launch_bounds__(1024) void k_detect(const int* __restrict__ ei, int* __restrict__ flag,
                                                 int* __restrict__ gwp, int E){
  int t = threadIdx.x;
  if (t == 0) *flag = 0;
  if (t < NB) gwp[t * GWP_STRIDE] = t * SEG;
  __syncthreads();
  long long step = E / 1024; if (step < 1) step = 1;
  long long pos = 2LL * ((long long)t * step) + 1;
  if (pos < 2LL * E){
    if (ei[pos] != 0) atomicOr(flag, 1);  // nonzero odd word => int32
  }
}

// ---- pre-pack W1 into MFMA B-frag layout
__global__ __launch_bounds__(256) void k_packW1(const float* __restrict__ W1,
                                                unsigned short* __restrict__ pw){
  int s = threadIdx.x;
  for (int slot = s; slot < 1024; slot += 256){
    int col = slot & 15, kg = (slot >> 4) & 3, t = slot >> 6;
    unsigned short o[8];
    #pragma unroll
    for (int e = 0; e < 8; ++e)
      o[e] = f2bf(W1[(t * 32 + kg * 8 + e) * HDIM + col]);
    uint4 v; __builtin_memcpy(&v, o, 16);
    *(uint4*)(pw + (size_t)slot * 8) = v;
  }
}

// ---- block-local counting sort, edges in regs, k->bucket LDS map
__global__ __launch_bounds__(1024) void k_binscatter(const int* __restrict__ ei, const int* __restrict__ flag,
                                                     int* __restrict__ gwp, int* __restrict__ pairs,
                                                     int E, int NPB){
  __shared__ int bh[NB];              // hist, then local write-ptr
  __shared__ int lex[NB + 1];         // local exclusive scan
  __shared__ int bb2[NB];             // reserved global base per bucket
  __shared__ int wsum[16];
  __shared__ unsigned short kb[SCHUNK];  // k -> bucket map
  __shared__ int stage[SCHUNK];
  int t = threadIdx.x;
  int e0 = blockIdx.x * SCHUNK;
  int e1 = min(E, e0 + SCHUNK);
  int cnt = e1 - e0;
  if (cnt <= 0) return;
  int is32 = *flag;
  const uint2* ei2 = (const uint2*)ei;
  int pk[EPT]; int bi[EPT];
  #pragma unroll
  for (int j = 0; j < EPT; ++j){
    int e = e0 + t + j * 1024;
    if (e < e1){
      int src, dst;
      if (is32){ src = ei[e]; dst = ei[(size_t)E + e]; }
      else     { src = (int)ei2[e].x; dst = (int)ei2[(size_t)E + e].x; }
      int b = dst / NPB;
      pk[j] = src | ((dst - b * NPB) << 20);
      bi[j] = b;
    } else bi[j] = -1;
  }
  if (t < NB) bh[t] = 0;
  __syncthreads();
  // A: local hist from regs
  #pragma unroll
  for (int j = 0; j < EPT; ++j) if (bi[j] >= 0) atomicAdd(&bh[bi[j]], 1);
  __syncthreads();
  // B: block scan over NB buckets, reserve global run in each bucket's segment
  {
    int lane = t & 63, w = t >> 6;
    int v = (t < NB) ? bh[t] : 0;
    int xs = v;
    #pragma unroll
    for (int off = 1; off < 64; off <<= 1){
      int y = __shfl_up(xs, off);
      if (lane >= off) xs += y;
    }
    if (lane == 63) wsum[w] = xs;
    __syncthreads();
    int woff = 0;
    for (int k = 0; k < w; ++k) woff += wsum[k];
    int excl = woff + xs - v;
    if (t < NB){
      lex[t] = excl;
      bb2[t] = v ? atomicAdd(&gwp[t * GWP_STRIDE], v) : 0;
      bh[t] = excl;               // becomes local write ptr (only own t touched)
    }
    if (t == NB - 1) lex[NB] = excl + v;
  }
  __syncthreads();
  // C: scatter into LDS stage from regs; record bucket in kb
  #pragma unroll
  for (int j = 0; j < EPT; ++j){
    if (bi[j] >= 0){
      int idx = atomicAdd(&bh[bi[j]], 1);
      stage[idx] = pk[j];
      kb[idx] = (unsigned short)bi[j];
    }
  }
  __syncthreads();
  // D: coalesced copy-out; bucket from kb (no search)
  for (int k = t; k < cnt; k += 1024){
    int b = kb[k];
    pairs[bb2[b] + (k - lex[b])] = stage[k];
  }
}

// ---- per-bucket degree -> dinv
__global__ __launch_bounds__(256) void k_deg(const int* __restrict__ pairs, const int* __restrict__ gwp,
                                             float* __restrict__ dinv, int n, int NPB){
  __shared__ int h[NPB_MAX];
  int b = blockIdx.x, t = threadIdx.x;
  int cntE = gwp[b * GWP_STRIDE] - b * SEG;
  for (int k = t; k < NPB; k += 256) h[k] = 0;
  __syncthreads();
  const int* pb = pairs + (size_t)b * SEG;
  for (int k = t; k < cntE; k += 256) atomicAdd(&h[((unsigned)pb[k]) >> 20], 1);
  __syncthreads();
  for (int k = t; k < NPB; k += 256){
    int node = b * NPB + k;
    if (node < n) dinv[node] = rsqrtf((float)(h[k] + 1));   // +1 self loop
  }
}

// ---- hs1 = dinv * (x @ W1) via MFMA 16x16x32 bf16, multi-tile per wave.
__global__ __launch_bounds__(256) void k_gemm1(const float* __restrict__ x, const unsigned short* __restrict__ pw,
                                               const float* __restrict__ dinv, unsigned short* __restrict__ hs1,
                                               int n){
  int lane = threadIdx.x & 63;
  int col = lane & 15;            // A-row / B-col / D-col
  int kg  = lane >> 4;            // k-group (0..3)
  int nt = (n + 15) >> 4;
  const short8* pw8 = (const short8*)pw;
  short8 B[16];
  #pragma unroll
  for (int t = 0; t < 16; ++t) B[t] = pw8[t * 64 + kg * 16 + col];
  int nw = gridDim.x * 4;
  for (int wid = blockIdx.x * 4 + (threadIdx.x >> 6); wid < nt; wid += nw){
    int row = wid * 16 + col;
    const float* xr = x + (size_t)min(row, n - 1) * F_IN;
    floatx4 acc = {0.f, 0.f, 0.f, 0.f};
    #pragma unroll
    for (int t = 0; t < 16; ++t){
      const float4* p = (const float4*)(xr + t * 32 + kg * 8);
      float4 u0 = p[0];
      float4 u1 = p[1];
      acc = __builtin_amdgcn_mfma_f32_16x16x32_bf16(pack8(u0, u1), B[t], acc, 0, 0, 0);
    }
    #pragma unroll
    for (int r = 0; r < 4; ++r){
      int orow = wid * 16 + kg * 4 + r;
      if (orow < n) hs1[(size_t)orow * HDIM + col] = f2bf(dinv[orow] * acc[r]);
    }
  }
}

// ---- conv1 aggregate (LDS scatter) + b1 + relu + @W2 + dinv -> hs2 bf16 [N][8]
// block per bucket; 2 threads per edge (each half = 8 bf16 of hs1 row).
__global__ __launch_bounds__(512) void k_agg1f(const unsigned short* __restrict__ hs1,
    const int* __restrict__ pairs, const int* __restrict__ gwp,
    const float* __restrict__ dinv, const float* __restrict__ b1,
    const float* __restrict__ W2, unsigned short* __restrict__ hs2, int n, int NPB){
  __shared__ float acc[NPB_MAX * 17];          // pad 17 -> banks spread by dl
  int b = blockIdx.x, t = threadIdx.x;
  int cntE = gwp[b * GWP_STRIDE] - b * SEG;
  for (int k = t; k < NPB * 17; k += 512) acc[k] = 0.f;
  __syncthreads();
  const uint4* hv = (const uint4*)hs1;         // row = 2 uint4
  const int* pb = pairs + (size_t)b * SEG;
  int half = t & 1;
  for (int k = (t >> 1); k < cntE; k += 256){
    int p = pb[k];
    int src = p & 0xFFFFF;
    int dl = ((unsigned)p) >> 20;
    uint4 v = hv[(size_t)src * 2 + half];
    float* a = acc + dl * 17 + half * 8;
    atomicAdd(a + 0, ulo(v.x)); atomicAdd(a + 1, uhi(v.x));
    atomicAdd(a + 2, ulo(v.y)); atomicAdd(a + 3, uhi(v.y));
    atomicAdd(a + 4, ulo(v.z)); atomicAdd(a + 5, uhi(v.z));
    atomicAdd(a + 6, ulo(v.w)); atomicAdd(a + 7, uhi(v.w));
  }
  __syncthreads();
  // per-node epilogue (thread per node)
  for (int i = t; i < NPB; i += 512){
    int node = b * NPB + i;
    if (node >= n) break;
    float dv = dinv[node];
    uint4 s0 = hv[(size_t)node * 2], s1 = hv[(size_t)node * 2 + 1];
    float self[16] = {ulo(s0.x), uhi(s0.x), ulo(s0.y), uhi(s0.y),
                      ulo(s0.z), uhi(s0.z), ulo(s0.w), uhi(s0.w),
                      ulo(s1.x), uhi(s1.x), ulo(s1.y), uhi(s1.y),
                      ulo(s1.z), uhi(s1.z), ulo(s1.w), uhi(s1.w)};
    float r[16];
    #pragma unroll
    for (int j = 0; j < 16; ++j)
      r[j] = fmaxf(fmaf(dv, acc[i * 17 + j] + self[j], b1[j]), 0.f);
    unsigned short o[8];
    #pragma unroll
    for (int c = 0; c < CDIM; ++c){
      float s = 0.f;
      #pragma unroll
      for (int j = 0; j < 16; ++j) s = fmaf(r[j], W2[j * CDIM + c], s);
      o[c] = f2bf(dv * s);
    }
    o[5] = 0; o[6] = 0; o[7] = 0;
    uint4 v; __builtin_memcpy(&v, o, 16);
    *(uint4*)(hs2 + (size_t)node * 8) = v;
  }
}

// ---- conv2 aggregate (LDS scatter) + b2 + mlp + log_softmax -> out [N][5] f32
__global__ __launch_bounds__(512) void k_agg2f(const unsigned short* __restrict__ hs2,
    const int* __restrict__ pairs, const int* __restrict__ gwp,
    const float* __restrict__ dinv, const float* __restrict__ b2,
    const float* __restrict__ W3, const float* __restrict__ b3,
    const float* __restrict__ W4, const float* __restrict__ b4,
    float* __restrict__ out, int n, int NPB){
  __shared__ float acc[NPB_MAX * 9];           // pad 9 -> banks spread by dl
  int b = blockIdx.x, t = threadIdx.x;
  int cntE = gwp[b * GWP_STRIDE] - b * SEG;
  for (int k = t; k < NPB * 9; k += 512) acc[k] = 0.f;
  __syncthreads();
  const uint4* hv = (const uint4*)hs2;         // row = 1 uint4
  const int* pb = pairs + (size_t)b * SEG;
  for (int k = t; k < cntE; k += 512){
    int p = pb[k];
    int src = p & 0xFFFFF;
    int dl = ((unsigned)p) >> 20;
    uint4 v = hv[src];
    float* a = acc + dl * 9;
    atomicAdd(a + 0, ulo(v.x)); atomicAdd(a + 1, uhi(v.x));
    atomicAdd(a + 2, ulo(v.y)); atomicAdd(a + 3, uhi(v.y));
    atomicAdd(a + 4, ulo(v.z));
  }
  __syncthreads();
  // per-node epilogue (thread per node): a(5) -> h3(32) relu -> q(5) -> logsoftmax
  for (int i = t; i < NPB; i += 512){
    int node = b * NPB + i;
    if (node >= n) break;
    float dv = dinv[node];
    uint4 sv = hv[node];
    float a0 = fmaf(dv, acc[i * 9 + 0] + ulo(sv.x), b2[0]);
    float a1 = fmaf(dv, acc[i * 9 + 1] + uhi(sv.x), b2[1]);
    float a2 = fmaf(dv, acc[i * 9 + 2] + ulo(sv.y), b2[2]);
    float a3 = fmaf(dv, acc[i * 9 + 3] + uhi(sv.y), b2[3]);
    float a4 = fmaf(dv, acc[i * 9 + 4] + ulo(sv.z), b2[4]);
    float q[CDIM];
    #pragma unroll
    for (int c = 0; c < CDIM; ++c) q[c] = b4[c];
    #pragma unroll
    for (int m = 0; m < 32; ++m){
      float h3 = b3[m];
      h3 = fmaf(a0, W3[0 * 32 + m], h3);
      h3 = fmaf(a1, W3[1 * 32 + m], h3);
      h3 = fmaf(a2, W3[2 * 32 + m], h3);
      h3 = fmaf(a3, W3[3 * 32 + m], h3);
      h3 = fmaf(a4, W3[4 * 32 + m], h3);
      h3 = fmaxf(h3, 0.f);
      #pragma unroll
      for (int c = 0; c < CDIM; ++c) q[c] = fmaf(h3, W4[m * CDIM + c], q[c]);
    }
    float mx = fmaxf(fmaxf(fmaxf(q[0], q[1]), fmaxf(q[2], q[3])), q[4]);
    float sum = expf(q[0] - mx) + expf(q[1] - mx) + expf(q[2] - mx) +
                expf(q[3] - mx) + expf(q[4] - mx);
    float lse = mx + logf(sum);
    float* op = out + (size_t)node * CDIM;
    #pragma unroll
    for (int c = 0; c < CDIM; ++c) op[c] = q[c] - lse;
  }
}

extern "C" void kernel_launch(void* const* d_in, const int* in_sizes, int n_in,
                              void* d_out, int out_size, void* d_ws, size_t ws_size,
                              hipStream_t stream){
  const float* x  = (const float*)d_in[0];
  const int*   ei = (const int*)d_in[1];
  const float* W1 = (const float*)d_in[2];
  const float* b1 = (const float*)d_in[3];
  const float* W2 = (const float*)d_in[4];
  const float* b2 = (const float*)d_in[5];
  const float* W3 = (const float*)d_in[6];
  const float* b3 = (const float*)d_in[7];
  const float* W4 = (const float*)d_in[8];
  const float* b4 = (const float*)d_in[9];
  float* out = (float*)d_out;

  int N = in_sizes[0] / F_IN;
  int E = in_sizes[1] / 2;
  int NPB = (N + NB - 1) / NB;      // nodes per bucket (196 for N=100000)

  char* ws = (char*)d_ws;
  size_t off = 0;
  auto alloc = [&](size_t bytes) -> char* {
    char* p = ws + off;
    off += (bytes + 255) & ~(size_t)255;
    return p;
  };
  int* flag  = (int*)alloc(4);
  int* gwp   = (int*)alloc((size_t)NB * GWP_STRIDE * 4);
  float* dinv= (float*)alloc((size_t)N * 4);
  unsigned short* pw = (unsigned short*)alloc((size_t)F_IN * HDIM * 2);
  int* pairs = (int*)alloc((size_t)NB * SEG * 4);   // segmented, 32 MB
  unsigned short* hs1 = (unsigned short*)alloc((size_t)N * HDIM * 2);
  unsigned short* hs2 = (unsigned short*)alloc((size_t)N * 8 * 2);
  (void)ws_size; (void)n_in; (void)out_size;

  k_detect<<<1, 1024, 0, stream>>>(ei, flag, gwp, E);
  k_packW1<<<1, 256, 0, stream>>>(W1, pw);
  int sblocks = (E + SCHUNK - 1) / SCHUNK;
  k_binscatter<<<sblocks, 1024, 0, stream>>>(ei, flag, gwp, pairs, E, NPB);
  k_deg<<<NB, 256, 0, stream>>>(pairs, gwp, dinv, N, NPB);
  k_gemm1<<<768, 256, 0, stream>>>(x, pw, dinv, hs1, N);
  k_agg1f<<<NB, 512, 0, stream>>>(hs1, pairs, gwp, dinv, b1, W2, hs2, N, NPB);
  k_agg2f<<<NB, 512, 0, stream>>>(hs2, pairs, gwp, dinv, b2, W3, b3, W4, b4, out, N, NPB);
}

// Round 11
// 257.949 us; speedup vs baseline: 3.1099x; 3.1099x over previous
//
#include <hip/hip_runtime.h>
#include <hip/hip_bf16.h>

// GCN: conv1(512->16) + relu + conv2(16->5) + mlp(5->32->5) + log_softmax
// out[dst] = dinv[dst]*(sum_{src in N(dst)} hs[src] + hs[dst]) + b,  hs = dinv*(h@W)
// CSR build: segmented 2-level bucket sort, single edge pass; segmented ssrc
// (no compact scan). Aggregation: gather + shuffle reduce (wave per node).
// gemm1 via MFMA with pre-packed register-resident W1.

#define F_IN 512
#define HDIM 16
#define CDIM 5
#define NB   1024      // dst-range buckets
#define SEG  8192      // per-bucket segment capacity (mean 6250, +24 sigma)
#define GWP_STRIDE 16  // pad gwp counters to one per 64B line
#define EPT  10        // edges per thread in binscatter
#define SCHUNK (1024*EPT)
#define CAP  8192      // per-bucket LDS staging in k_bucket (ints)

typedef __attribute__((ext_vector_type(8))) short short8;
typedef __attribute__((ext_vector_type(4))) float floatx4;

__device__ inline float bf2f(unsigned short u){
  unsigned int i = ((unsigned int)u) << 16; float f; __builtin_memcpy(&f, &i, 4); return f;
}
__device__ inline unsigned short f2bf(float x){
  unsigned int i; __builtin_memcpy(&i, &x, 4);
  unsigned int r = i + 0x7FFFu + ((i >> 16) & 1u);
  return (unsigned short)(r >> 16);
}
__device__ inline float ulo(unsigned int u){
  unsigned int v = u << 16; float f; __builtin_memcpy(&f, &v, 4); return f;
}
__device__ inline float uhi(unsigned int u){
  unsigned int v = u & 0xFFFF0000u; float f; __builtin_memcpy(&f, &v, 4); return f;
}
__device__ inline short8 pack8(float4 u0, float4 u1){
  unsigned short o[8] = {f2bf(u0.x), f2bf(u0.y), f2bf(u0.z), f2bf(u0.w),
                         f2bf(u1.x), f2bf(u1.y), f2bf(u1.z), f2bf(u1.w)};
  short8 r; __builtin_memcpy(&r, o, 16); return r;
}

// ---- single block: init flag + gwp bases + detect int64/int32 + pack W1
__global__ __launch_bounds__(1024) void k_detect(const int* __restrict__ ei, int* __restrict__ flag,
                                                 int* __restrict__ gwp, const float* __restrict__ W1,
                                                 unsigned short* __restrict__ pw, int E){
  int t = threadIdx.x;
  if (t == 0) *flag = 0;
  gwp[t * GWP_STRIDE] = t * SEG;          // 1024 threads == NB
  // pack W1 into MFMA B-frag layout: slot = t
  {
    int col = t & 15, kg = (t >> 4) & 3, tt = t >> 6;
    unsigned short o[8];
    #pragma unroll
    for (int e = 0; e < 8; ++e)
      o[e] = f2bf(W1[(tt * 32 + kg * 8 + e) * HDIM + col]);
    uint4 v; __builtin_memcpy(&v, o, 16);
    *(uint4*)(pw + (size_t)t * 8) = v;
  }
  __syncthreads();
  long long step = E / 1024; if (step < 1) step = 1;
  long long pos = 2LL * ((long long)t * step) + 1;
  if (pos < 2LL * E){
    if (ei[pos] != 0) atomicOr(flag, 1);  // nonzero odd word => int32
  }
}

// ---- block-local counting sort, edges in regs, k->bucket LDS map (no search)
__global__ __launch_bounds__(1024) void k_binscatter(const int* __restrict__ ei, const int* __restrict__ flag,
                                                     int* __restrict__ gwp, int* __restrict__ pairs,
                                                     int E, int NPB){
  __shared__ int bh[NB];              // hist, then local write-ptr
  __shared__ int lex[NB];             // local exclusive scan
  __shared__ int bb2[NB];             // reserved global base per bucket
  __shared__ int wsum[16];
  __shared__ unsigned short kb[SCHUNK];  // k -> bucket map
  __shared__ int stage[SCHUNK];
  int t = threadIdx.x;
  int e0 = blockIdx.x * SCHUNK;
  int e1 = min(E, e0 + SCHUNK);
  int cnt = e1 - e0;
  if (cnt <= 0) return;
  int is32 = *flag;
  const uint2* ei2 = (const uint2*)ei;
  int pk[EPT]; int bi[EPT];
  #pragma unroll
  for (int j = 0; j < EPT; ++j){
    int e = e0 + t + j * 1024;
    if (e < e1){
      int src, dst;
      if (is32){ src = ei[e]; dst = ei[(size_t)E + e]; }
      else     { src = (int)ei2[e].x; dst = (int)ei2[(size_t)E + e].x; }
      int b = dst / NPB;
      pk[j] = src | ((dst - b * NPB) << 20);
      bi[j] = b;
    } else bi[j] = -1;
  }
  bh[t] = 0;
  __syncthreads();
  // A: local hist from regs
  #pragma unroll
  for (int j = 0; j < EPT; ++j) if (bi[j] >= 0) atomicAdd(&bh[bi[j]], 1);
  __syncthreads();
  // B: block scan (t == bucket), reserve global run in the bucket's segment
  {
    int lane = t & 63, w = t >> 6;
    int v = bh[t];
    int xs = v;
    #pragma unroll
    for (int off = 1; off < 64; off <<= 1){
      int y = __shfl_up(xs, off);
      if (lane >= off) xs += y;
    }
    if (lane == 63) wsum[w] = xs;
    __syncthreads();
    int woff = 0;
    for (int k = 0; k < w; ++k) woff += wsum[k];
    int excl = woff + xs - v;
    lex[t] = excl;
    bb2[t] = v ? atomicAdd(&gwp[t * GWP_STRIDE], v) : 0;
    __syncthreads();              // all reads of bh done before overwrite
    bh[t] = excl;                 // becomes local write ptr
  }
  __syncthreads();
  // C: scatter into LDS stage from regs; record bucket in kb
  #pragma unroll
  for (int j = 0; j < EPT; ++j){
    if (bi[j] >= 0){
      int idx = atomicAdd(&bh[bi[j]], 1);
      stage[idx] = pk[j];
      kb[idx] = (unsigned short)bi[j];
    }
  }
  __syncthreads();
  // D: coalesced copy-out; bucket from kb (no search)
  for (int k = t; k < cnt; k += 1024){
    int b = kb[k];
    pairs[bb2[b] + (k - lex[b])] = stage[k];
  }
}

// ---- per-bucket CSR finalize: 8-way sub-hist, shfl scan, LDS sort,
//      coalesced flush into SEGMENTED ssrc; emits rowptr + rowdeg + dinv.
__global__ __launch_bounds__(512) void k_bucket(const int* __restrict__ pairs, const int* __restrict__ gwp,
                                                int* __restrict__ rowptr, int* __restrict__ rowdeg,
                                                float* __restrict__ dinv, int* __restrict__ ssrc,
                                                int NPB, int n){
  __shared__ int lcnt[8][128];    // sub-hists, then sub-write-ptrs
  __shared__ int tot[128];
  __shared__ int lexcl[128];
  __shared__ int w0sum;
  __shared__ int stage[CAP];
  int b = blockIdx.x;
  int t = threadIdx.x;
  int g = t >> 6;                 // 8 groups of 64 threads
  int node0 = b * NPB;
  int pbase = b * SEG;
  int obase = b * SEG;            // segmented output
  int cntE = gwp[b * GWP_STRIDE] - b * SEG;
  for (int k = t & 63; k < 128; k += 64) lcnt[g][k] = 0;
  __syncthreads();
  for (int k = t; k < cntE; k += 512){
    unsigned int v = (unsigned int)pairs[pbase + k];
    atomicAdd(&lcnt[g][v >> 20], 1);
  }
  __syncthreads();
  if (t < 128){
    int c = 0;
    #pragma unroll
    for (int gg = 0; gg < 8; ++gg){
      int tmp = lcnt[gg][t];
      lcnt[gg][t] = c;
      c += tmp;
    }
    tot[t] = c;
  }
  __syncthreads();
  // exclusive scan over tot[0..127] (2 waves + carry)
  int lane = t & 63;
  int v = (t < 128) ? tot[t] : 0;
  int xs = v;
  #pragma unroll
  for (int off = 1; off < 64; off <<= 1){
    int y = __shfl_up(xs, off);
    if (lane >= off) xs += y;
  }
  if (t == 63) w0sum = xs;
  __syncthreads();
  if (t < 128) lexcl[t] = xs - v + ((t >= 64) ? w0sum : 0);
  __syncthreads();
  if (t < NPB){
    int node = node0 + t;
    if (node < n){
      rowptr[node] = obase + lexcl[t];
      rowdeg[node] = tot[t];
      dinv[node] = rsqrtf((float)(tot[t] + 1));            // +1 self loop
    }
  }
  if (t < 128){
    #pragma unroll
    for (int gg = 0; gg < 8; ++gg) lcnt[gg][t] += lexcl[t];
  }
  __syncthreads();
  for (int k = t; k < cntE; k += 512){
    unsigned int v2 = (unsigned int)pairs[pbase + k];
    int idx = atomicAdd(&lcnt[g][v2 >> 20], 1);
    int src = (int)(v2 & 0xFFFFFu);
    if (idx < CAP) stage[idx] = src;
    else ssrc[obase + idx] = src;
  }
  __syncthreads();
  int m = cntE < CAP ? cntE : CAP;
  for (int k = t; k < m; k += 512) ssrc[obase + k] = stage[k];
}

// ---- hs1 = dinv * (x @ W1) via MFMA 16x16x32 bf16, multi-tile per wave.
__global__ __launch_bounds__(256) void k_gemm1(const float* __restrict__ x, const unsigned short* __restrict__ pw,
                                               const float* __restrict__ dinv, unsigned short* __restrict__ hs1,
                                               int n){
  int lane = threadIdx.x & 63;
  int col = lane & 15;            // A-row / B-col / D-col
  int kg  = lane >> 4;            // k-group (0..3)
  int nt = (n + 15) >> 4;
  const short8* pw8 = (const short8*)pw;
  short8 B[16];
  #pragma unroll
  for (int t = 0; t < 16; ++t) B[t] = pw8[t * 64 + kg * 16 + col];
  int nw = gridDim.x * 4;
  for (int wid = blockIdx.x * 4 + (threadIdx.x >> 6); wid < nt; wid += nw){
    int row = wid * 16 + col;
    const float* xr = x + (size_t)min(row, n - 1) * F_IN;
    floatx4 acc = {0.f, 0.f, 0.f, 0.f};
    #pragma unroll
    for (int t = 0; t < 16; ++t){
      const float4* p = (const float4*)(xr + t * 32 + kg * 8);
      float4 u0 = p[0];
      float4 u1 = p[1];
      acc = __builtin_amdgcn_mfma_f32_16x16x32_bf16(pack8(u0, u1), B[t], acc, 0, 0, 0);
    }
    #pragma unroll
    for (int r = 0; r < 4; ++r){
      int orow = wid * 16 + kg * 4 + r;
      if (orow < n) hs1[(size_t)orow * HDIM + col] = f2bf(dinv[orow] * acc[r]);
    }
  }
}

// ---- conv1 aggregate + b1 + relu + @W2 + dinv scale -> hs2 bf16 [N][8]
// wave per node; 2 lanes per edge (each lane: uint4 = 8 bf16 = half hs1 row).
__global__ __launch_bounds__(256) void k_agg1(const unsigned short* __restrict__ hs1,
    const int* __restrict__ rowptr, const int* __restrict__ rowdeg, const int* __restrict__ ssrc,
    const float* __restrict__ dinv, const float* __restrict__ b1,
    const float* __restrict__ W2, unsigned short* __restrict__ hs2, int n){
  int lane = threadIdx.x & 63;
  int i = blockIdx.x * 4 + (threadIdx.x >> 6);
  if (i >= n) return;
  int slot = lane >> 1, half = lane & 1;
  int beg = rowptr[i], end = beg + rowdeg[i];
  const uint4* hv = (const uint4*)hs1;                 // row = 2 uint4
  float acc[8];
  #pragma unroll
  for (int k = 0; k < 8; ++k) acc[k] = 0.f;
  for (int e = beg + slot; e < end; e += 32){
    int src = ssrc[e];
    uint4 v = hv[(size_t)src * 2 + half];
    acc[0] += ulo(v.x); acc[1] += uhi(v.x);
    acc[2] += ulo(v.y); acc[3] += uhi(v.y);
    acc[4] += ulo(v.z); acc[5] += uhi(v.z);
    acc[6] += ulo(v.w); acc[7] += uhi(v.w);
  }
  #pragma unroll
  for (int off = 2; off < 64; off <<= 1){
    #pragma unroll
    for (int k = 0; k < 8; ++k) acc[k] += __shfl_xor(acc[k], off);
  }
  uint4 sv = hv[(size_t)i * 2 + half];
  float self[8] = {ulo(sv.x), uhi(sv.x), ulo(sv.y), uhi(sv.y),
                   ulo(sv.z), uhi(sv.z), ulo(sv.w), uhi(sv.w)};
  float dv = dinv[i];
  const float4* b1v = (const float4*)b1;
  float4 bl = b1v[half * 2], bh = b1v[half * 2 + 1];
  float r[8];
  r[0] = fmaxf(fmaf(dv, acc[0] + self[0], bl.x), 0.f);
  r[1] = fmaxf(fmaf(dv, acc[1] + self[1], bl.y), 0.f);
  r[2] = fmaxf(fmaf(dv, acc[2] + self[2], bl.z), 0.f);
  r[3] = fmaxf(fmaf(dv, acc[3] + self[3], bl.w), 0.f);
  r[4] = fmaxf(fmaf(dv, acc[4] + self[4], bh.x), 0.f);
  r[5] = fmaxf(fmaf(dv, acc[5] + self[5], bh.y), 0.f);
  r[6] = fmaxf(fmaf(dv, acc[6] + self[6], bh.z), 0.f);
  r[7] = fmaxf(fmaf(dv, acc[7] + self[7], bh.w), 0.f);
  const float* w2 = W2 + half * 8 * CDIM;
  float p[CDIM];
  #pragma unroll
  for (int c = 0; c < CDIM; ++c){
    float s = 0.f;
    #pragma unroll
    for (int k = 0; k < 8; ++k) s = fmaf(r[k], w2[k * CDIM + c], s);
    p[c] = s;
  }
  #pragma unroll
  for (int c = 0; c < CDIM; ++c) p[c] += __shfl_xor(p[c], 1);
  if (lane == 0){
    unsigned short o[8];
    #pragma unroll
    for (int c = 0; c < CDIM; ++c) o[c] = f2bf(dv * p[c]);
    o[5] = 0; o[6] = 0; o[7] = 0;
    uint4 v; __builtin_memcpy(&v, o, 16);
    *(uint4*)(hs2 + (size_t)i * 8) = v;
  }
}

// ---- conv2 aggregate + b2 + mlp + log_softmax -> out [N][5] f32
// wave per node; 1 lane per edge (uint4 = full hs2 row).
__global__ __launch_bounds__(256) void k_agg2(const unsigned short* __restrict__ hs2,
    const int* __restrict__ rowptr, const int* __restrict__ rowdeg, const int* __restrict__ ssrc,
    const float* __restrict__ dinv, const float* __restrict__ b2,
    const float* __restrict__ W3, const float* __restrict__ b3,
    const float* __restrict__ W4, const float* __restrict__ b4,
    float* __restrict__ out, int n){
  int lane = threadIdx.x & 63;
  int i = blockIdx.x * 4 + (threadIdx.x >> 6);
  if (i >= n) return;
  int beg = rowptr[i], end = beg + rowdeg[i];
  const uint4* hv = (const uint4*)hs2;                 // row = 1 uint4
  float acc[CDIM];
  #pragma unroll
  for (int k = 0; k < CDIM; ++k) acc[k] = 0.f;
  for (int e = beg + lane; e < end; e += 64){
    int src = ssrc[e];
    uint4 v = hv[src];
    acc[0] += ulo(v.x); acc[1] += uhi(v.x);
    acc[2] += ulo(v.y); acc[3] += uhi(v.y);
    acc[4] += ulo(v.z);
  }
  #pragma unroll
  for (int off = 1; off < 64; off <<= 1){
    #pragma unroll
    for (int k = 0; k < CDIM; ++k) acc[k] += __shfl_xor(acc[k], off);
  }
  float dv = dinv[i];
  uint4 sv = hv[i];
  float a0 = fmaf(dv, acc[0] + ulo(sv.x), b2[0]);
  float a1 = fmaf(dv, acc[1] + uhi(sv.x), b2[1]);
  float a2 = fmaf(dv, acc[2] + ulo(sv.y), b2[2]);
  float a3 = fmaf(dv, acc[3] + uhi(sv.y), b2[3]);
  float a4 = fmaf(dv, acc[4] + ulo(sv.z), b2[4]);
  int m = lane & 31;
  float h3 = b3[m];
  h3 = fmaf(a0, W3[0 * 32 + m], h3);
  h3 = fmaf(a1, W3[1 * 32 + m], h3);
  h3 = fmaf(a2, W3[2 * 32 + m], h3);
  h3 = fmaf(a3, W3[3 * 32 + m], h3);
  h3 = fmaf(a4, W3[4 * 32 + m], h3);
  h3 = fmaxf(h3, 0.f);
  float q0 = h3 * W4[m * CDIM + 0], q1 = h3 * W4[m * CDIM + 1], q2 = h3 * W4[m * CDIM + 2];
  float q3 = h3 * W4[m * CDIM + 3], q4 = h3 * W4[m * CDIM + 4];
  #pragma unroll
  for (int off = 1; off < 32; off <<= 1){
    q0 += __shfl_xor(q0, off); q1 += __shfl_xor(q1, off); q2 += __shfl_xor(q2, off);
    q3 += __shfl_xor(q3, off); q4 += __shfl_xor(q4, off);
  }
  q0 += b4[0]; q1 += b4[1]; q2 += b4[2]; q3 += b4[3]; q4 += b4[4];
  float mx = fmaxf(fmaxf(fmaxf(q0, q1), fmaxf(q2, q3)), q4);
  float sum = expf(q0 - mx) + expf(q1 - mx) + expf(q2 - mx) + expf(q3 - mx) + expf(q4 - mx);
  float lse = mx + logf(sum);
  if (lane < CDIM){
    float v = q0;
    if (lane == 1) v = q1;
    if (lane == 2) v = q2;
    if (lane == 3) v = q3;
    if (lane == 4) v = q4;
    out[(size_t)i * CDIM + lane] = v - lse;
  }
}

extern "C" void kernel_launch(void* const* d_in, const int* in_sizes, int n_in,
                              void* d_out, int out_size, void* d_ws, size_t ws_size,
                              hipStream_t stream){
  const float* x  = (const float*)d_in[0];
  const int*   ei = (const int*)d_in[1];
  const float* W1 = (const float*)d_in[2];
  const float* b1 = (const float*)d_in[3];
  const float* W2 = (const float*)d_in[4];
  const float* b2 = (const float*)d_in[5];
  const float* W3 = (const float*)d_in[6];
  const float* b3 = (const float*)d_in[7];
  const float* W4 = (const float*)d_in[8];
  const float* b4 = (const float*)d_in[9];
  float* out = (float*)d_out;

  int N = in_sizes[0] / F_IN;
  int E = in_sizes[1] / 2;
  int NPB = (N + NB - 1) / NB;      // nodes per bucket (98 for N=100000)

  char* ws = (char*)d_ws;
  size_t off = 0;
  auto alloc = [&](size_t bytes) -> char* {
    char* p = ws + off;
    off += (bytes + 255) & ~(size_t)255;
    return p;
  };
  int* flag  = (int*)alloc(4);
  int* gwp   = (int*)alloc((size_t)NB * GWP_STRIDE * 4);
  int* rowptr= (int*)alloc((size_t)N * 4);
  int* rowdeg= (int*)alloc((size_t)N * 4);
  float* dinv= (float*)alloc((size_t)N * 4);
  unsigned short* pw = (unsigned short*)alloc((size_t)F_IN * HDIM * 2);
  int* pairs = (int*)alloc((size_t)NB * SEG * 4);   // segmented, 32 MB
  int* ssrc  = (int*)alloc((size_t)NB * SEG * 4);   // segmented, 32 MB
  unsigned short* hs1 = (unsigned short*)alloc((size_t)N * HDIM * 2);
  unsigned short* hs2 = (unsigned short*)alloc((size_t)N * 8 * 2);
  (void)ws_size; (void)n_in; (void)out_size;

  k_detect<<<1, 1024, 0, stream>>>(ei, flag, gwp, W1, pw, E);
  int sblocks = (E + SCHUNK - 1) / SCHUNK;
  k_binscatter<<<sblocks, 1024, 0, stream>>>(ei, flag, gwp, pairs, E, NPB);
  k_bucket<<<NB, 512, 0, stream>>>(pairs, gwp, rowptr, rowdeg, dinv, ssrc, NPB, N);
  k_gemm1<<<768, 256, 0, stream>>>(x, pw, dinv, hs1, N);
  k_agg1<<<(N + 3) / 4, 256, 0, stream>>>(hs1, rowptr, rowdeg, ssrc, dinv, b1, W2, hs2, N);
  k_agg2<<<(N + 3) / 4, 256, 0, stream>>>(hs2, rowptr, rowdeg, ssrc, dinv, b2, W3, b3, W4, b4, out, N);
}